// Round 6
// baseline (316.873 us; speedup 1.0000x reference)
//
#include <hip/hip_runtime.h>

#define F 128
#define SCAN_T 256
#define SCAN_ELEMS 16
#define SCAN_CHUNK (SCAN_T * SCAN_ELEMS)   // 4096 elements per block

static inline int align4i(int n) { return (n + 3) & ~3; }

// ---- pass 1: bucketed histogram + per-edge rank (one atomic pass) --------
// bucket = (dst << bshift) + (lane & bmask): dilutes per-cacheline atomic
// contention by B=1<<bshift while keeping each node's CSR range contiguous.
__global__ void hist_rank_kernel(const int* __restrict__ dst, int* __restrict__ deg,
                                 int* __restrict__ rank, int E, int bshift, int bmask) {
    int i = (blockIdx.x * blockDim.x + threadIdx.x) * 4;
    int sub = threadIdx.x & bmask;
    if (i + 3 < E) {
        int4 d = *(const int4*)&dst[i];
        int4 r;
        r.x = atomicAdd(&deg[(d.x << bshift) + sub], 1);
        r.y = atomicAdd(&deg[(d.y << bshift) + sub], 1);
        r.z = atomicAdd(&deg[(d.z << bshift) + sub], 1);
        r.w = atomicAdd(&deg[(d.w << bshift) + sub], 1);
        *(int4*)&rank[i] = r;
    } else {
        for (int k = i; k < E; ++k) rank[k] = atomicAdd(&deg[(dst[k] << bshift) + sub], 1);
    }
}

// ---- 3-level scan over M = B*N elements ----------------------------------
__global__ void scan_partial(const int* __restrict__ deg, int* __restrict__ bsum, int M) {
    int base = blockIdx.x * SCAN_CHUNK + threadIdx.x * SCAN_ELEMS;
    int s = 0;
    if (base + SCAN_ELEMS - 1 < M) {
#pragma unroll
        for (int q = 0; q < SCAN_ELEMS / 4; ++q) {
            int4 v = *(const int4*)&deg[base + q * 4];
            s += v.x + v.y + v.z + v.w;
        }
    } else {
        for (int i = base; i < M; ++i) s += deg[i];
    }
    for (int off = 32; off; off >>= 1) s += __shfl_down(s, off);
    __shared__ int wt[4];
    int wid = threadIdx.x >> 6;
    if ((threadIdx.x & 63) == 0) wt[wid] = s;
    __syncthreads();
    if (threadIdx.x == 0) bsum[blockIdx.x] = wt[0] + wt[1] + wt[2] + wt[3];
}

// level 2: 1024-thread LDS scan over up to 1024 block sums
__global__ void __launch_bounds__(1024)
scan_mid(const int* __restrict__ bsum, int* __restrict__ bpref,
         int* __restrict__ offs, int nB, int M) {
    __shared__ int sh[1024];
    int t = threadIdx.x;
    int v = (t < nB) ? bsum[t] : 0;
    sh[t] = v;
    __syncthreads();
    for (int off = 1; off < 1024; off <<= 1) {
        int u = (t >= off) ? sh[t - off] : 0;
        __syncthreads();
        sh[t] += u;
        __syncthreads();
    }
    if (t < nB) bpref[t] = sh[t] - v;          // exclusive
    if (t == 1023) offs[M] = sh[1023];         // total = E
}

// level 3: block-local scan + block offset, write offs (and cursor if set)
__global__ void scan_write(const int* __restrict__ deg, const int* __restrict__ bpref,
                           int* __restrict__ offs, int* __restrict__ cursor, int M) {
    int tid = threadIdx.x;
    int base = blockIdx.x * SCAN_CHUNK + tid * SCAN_ELEMS;
    int v[SCAN_ELEMS];
    int s = 0;
    bool full = (base + SCAN_ELEMS - 1 < M);
    if (full) {
#pragma unroll
        for (int q = 0; q < SCAN_ELEMS / 4; ++q) {
            int4 w = *(const int4*)&deg[base + q * 4];
            v[q * 4 + 0] = w.x; v[q * 4 + 1] = w.y; v[q * 4 + 2] = w.z; v[q * 4 + 3] = w.w;
            s += w.x + w.y + w.z + w.w;
        }
    } else {
#pragma unroll
        for (int k = 0; k < SCAN_ELEMS; ++k) {
            int i = base + k;
            v[k] = (i < M) ? deg[i] : 0;
            s += v[k];
        }
    }
    int inc = s;
    int lane = tid & 63, wid = tid >> 6;
    for (int off = 1; off < 64; off <<= 1) {
        int u = __shfl_up(inc, off);
        if (lane >= off) inc += u;
    }
    __shared__ int wt[4];
    if (lane == 63) wt[wid] = inc;
    __syncthreads();
    int wbase = 0;
    for (int w = 0; w < wid; ++w) wbase += wt[w];
    int run = bpref[blockIdx.x] + wbase + (inc - s);   // thread-exclusive prefix
    if (full) {
#pragma unroll
        for (int q = 0; q < SCAN_ELEMS / 4; ++q) {
            int4 r;
            r.x = run; run += v[q * 4 + 0];
            r.y = run; run += v[q * 4 + 1];
            r.z = run; run += v[q * 4 + 2];
            r.w = run; run += v[q * 4 + 3];
            *(int4*)&offs[base + q * 4] = r;
            if (cursor) *(int4*)&cursor[base + q * 4] = r;
        }
    } else {
#pragma unroll
        for (int k = 0; k < SCAN_ELEMS; ++k) {
            int i = base + k;
            if (i < M) {
                offs[i] = run;
                if (cursor) cursor[i] = run;
                run += v[k];
            }
        }
    }
}

// ---- pass 2 (rank path): atomic-free edge placement ----------------------
__global__ void scatter_pos(const int* __restrict__ src, const int* __restrict__ dst,
                            const int* __restrict__ rank, const int* __restrict__ offs,
                            int* __restrict__ csr_src, int E, int bshift, int bmask) {
    int i = (blockIdx.x * blockDim.x + threadIdx.x) * 4;
    int sub = threadIdx.x & bmask;
    if (i + 3 < E) {
        int4 s = *(const int4*)&src[i];
        int4 d = *(const int4*)&dst[i];
        int4 r = *(const int4*)&rank[i];
        csr_src[offs[(d.x << bshift) + sub] + r.x] = s.x;
        csr_src[offs[(d.y << bshift) + sub] + r.y] = s.y;
        csr_src[offs[(d.z << bshift) + sub] + r.z] = s.z;
        csr_src[offs[(d.w << bshift) + sub] + r.w] = s.w;
    } else {
        for (int k = i; k < E; ++k)
            csr_src[offs[(dst[k] << bshift) + sub] + rank[k]] = src[k];
    }
}

// fallback (small ws): atomic cursor reorder, B=1
__global__ void reorder_kernel(const int* __restrict__ src, const int* __restrict__ dst,
                               int* __restrict__ cursor, int* __restrict__ csr_src, int E) {
    int i = (blockIdx.x * blockDim.x + threadIdx.x) * 4;
    if (i + 3 < E) {
        int4 s = *(const int4*)&src[i];
        int4 d = *(const int4*)&dst[i];
        csr_src[atomicAdd(&cursor[d.x], 1)] = s.x;
        csr_src[atomicAdd(&cursor[d.y], 1)] = s.y;
        csr_src[atomicAdd(&cursor[d.z], 1)] = s.z;
        csr_src[atomicAdd(&cursor[d.w], 1)] = s.w;
    } else {
        for (int k = i; k < E; ++k) csr_src[atomicAdd(&cursor[dst[k]], 1)] = src[k];
    }
}

// ---- fused gather + self-loop + relu, 8x unrolled ------------------------
__global__ void gather_kernel(const float* __restrict__ x, const int* __restrict__ offs,
                              const int* __restrict__ csr_src, float* __restrict__ out,
                              int N, int bshift) {
    int t = blockIdx.x * blockDim.x + threadIdx.x;
    int node = t >> 5;
    if (node >= N) return;
    int c = t & 31;
    const float4* x4 = (const float4*)x;
    float4 acc = x4[node * 32 + c];            // self-loop term
    int b = offs[node << bshift];
    int e = offs[(node + 1) << bshift];
    int j = b;
    for (; j + 7 < e; j += 8) {
        int s0 = csr_src[j + 0], s1 = csr_src[j + 1], s2 = csr_src[j + 2], s3 = csr_src[j + 3];
        int s4 = csr_src[j + 4], s5 = csr_src[j + 5], s6 = csr_src[j + 6], s7 = csr_src[j + 7];
        float4 v0 = x4[s0 * 32 + c], v1 = x4[s1 * 32 + c], v2 = x4[s2 * 32 + c], v3 = x4[s3 * 32 + c];
        float4 v4 = x4[s4 * 32 + c], v5 = x4[s5 * 32 + c], v6 = x4[s6 * 32 + c], v7 = x4[s7 * 32 + c];
        acc.x += (v0.x + v1.x) + (v2.x + v3.x) + ((v4.x + v5.x) + (v6.x + v7.x));
        acc.y += (v0.y + v1.y) + (v2.y + v3.y) + ((v4.y + v5.y) + (v6.y + v7.y));
        acc.z += (v0.z + v1.z) + (v2.z + v3.z) + ((v4.z + v5.z) + (v6.z + v7.z));
        acc.w += (v0.w + v1.w) + (v2.w + v3.w) + ((v4.w + v5.w) + (v6.w + v7.w));
    }
    for (; j + 3 < e; j += 4) {
        int s0 = csr_src[j + 0], s1 = csr_src[j + 1], s2 = csr_src[j + 2], s3 = csr_src[j + 3];
        float4 v0 = x4[s0 * 32 + c], v1 = x4[s1 * 32 + c], v2 = x4[s2 * 32 + c], v3 = x4[s3 * 32 + c];
        acc.x += (v0.x + v1.x) + (v2.x + v3.x);
        acc.y += (v0.y + v1.y) + (v2.y + v3.y);
        acc.z += (v0.z + v1.z) + (v2.z + v3.z);
        acc.w += (v0.w + v1.w) + (v2.w + v3.w);
    }
    for (; j < e; ++j) {
        int s = csr_src[j];
        float4 v = x4[s * 32 + c];
        acc.x += v.x; acc.y += v.y; acc.z += v.z; acc.w += v.w;
    }
    acc.x = fmaxf(acc.x, 0.f); acc.y = fmaxf(acc.y, 0.f);
    acc.z = fmaxf(acc.z, 0.f); acc.w = fmaxf(acc.w, 0.f);
    ((float4*)out)[node * 32 + c] = acc;
}

// ---- launch --------------------------------------------------------------
extern "C" void kernel_launch(void* const* d_in, const int* in_sizes, int n_in,
                              void* d_out, int out_size, void* d_ws, size_t ws_size,
                              hipStream_t stream) {
    const float* x  = (const float*)d_in[0];
    const int*   ei = (const int*)d_in[1];     // [2, E]: src row then dst row
    float* out = (float*)d_out;

    int N = in_sizes[0] / F;          // 100000
    int E = in_sizes[1] / 2;          // 1600000
    const int* src = ei;
    const int* dst = ei + E;

    // primary: bucketed rank path, B = 8
    int bshift = 3, bmask = 7;
    int M = N << bshift;
    char* ws = (char*)d_ws;
    int* deg     = (int*)ws;                          // M
    int* offs    = deg + align4i(M);                  // M+1
    int* csr_src = offs + align4i(M + 1);             // E
    int* rank    = csr_src + align4i(E);              // E
    int* bsum    = rank + align4i(E);                 // 1024
    int* bpref   = bsum + 1024;                       // 1024
    size_t need = (size_t)((char*)(bpref + 1024) - ws);

    int eb = (E / 4 + 255) / 256 + 1;                 // blocks for 4-wide edge passes
    int gth = N * 32;

    if (ws_size >= need) {
        int nB = (M + SCAN_CHUNK - 1) / SCAN_CHUNK;   // 196 for M=800000 (<=1024)
        hipMemsetAsync(deg, 0, (size_t)M * sizeof(int), stream);
        hist_rank_kernel<<<eb, 256, 0, stream>>>(dst, deg, rank, E, bshift, bmask);
        scan_partial<<<nB, SCAN_T, 0, stream>>>(deg, bsum, M);
        scan_mid<<<1, 1024, 0, stream>>>(bsum, bpref, offs, nB, M);
        scan_write<<<nB, SCAN_T, 0, stream>>>(deg, bpref, offs, nullptr, M);
        scatter_pos<<<eb, 256, 0, stream>>>(src, dst, rank, offs, csr_src, E, bshift, bmask);
        gather_kernel<<<(gth + 255) / 256, 256, 0, stream>>>(x, offs, csr_src, out, N, bshift);
    } else {
        // fallback: B=1 cursor path (smaller footprint)
        bshift = 0; bmask = 0; M = N;
        deg     = (int*)ws;                           // N
        offs    = deg + align4i(N);                   // N+1
        csr_src = offs + align4i(N + 1);              // E
        int* cursor = csr_src + align4i(E);           // N
        bsum    = cursor + align4i(N);
        bpref   = bsum + 1024;
        int nB = (M + SCAN_CHUNK - 1) / SCAN_CHUNK;
        hipMemsetAsync(deg, 0, (size_t)M * sizeof(int), stream);
        hist_rank_kernel<<<eb, 256, 0, stream>>>(dst, deg, cursor /*scratch rank unused*/, E, 0, 0);
        // note: fallback reuses hist_rank writing ranks into cursor buffer; ranks
        // are then overwritten by scan_write's cursor init below.
        scan_partial<<<nB, SCAN_T, 0, stream>>>(deg, bsum, M);
        scan_mid<<<1, 1024, 0, stream>>>(bsum, bpref, offs, nB, M);
        scan_write<<<nB, SCAN_T, 0, stream>>>(deg, bpref, offs, cursor, M);
        reorder_kernel<<<eb, 256, 0, stream>>>(src, dst, cursor, csr_src, E);
        gather_kernel<<<(gth + 255) / 256, 256, 0, stream>>>(x, offs, csr_src, out, N, 0);
    }
}